// Round 13
// baseline (265.875 us; speedup 1.0000x reference)
//
#include <hip/hip_runtime.h>
#include <hip/hip_bf16.h>

#define NN 50000
#define EE 800000
#define FD 128
#define NG 128
#define NC 10
#define GBK 782   // (NN+63)/64
#define NBK 196   // (NN+255)/256
#define NBUCK 196 // dst buckets of 256 nodes
#define CHA 4096  // edges per chunk
#define NCHA 196  // ceil(EE/CHA)
#define CAPB 8192 // phase-B LDS staging capacity
#define CVB 199   // cvt blocks
#define FBK 3125  // fused agg+gemm blocks: NN/16 exactly

typedef __attribute__((ext_vector_type(8))) short bf16x8;
typedef __attribute__((ext_vector_type(4))) float f32x4;

__device__ __forceinline__ float bf2f(unsigned short u) {
    return __uint_as_float(((unsigned int)u) << 16);
}
__device__ __forceinline__ unsigned short f2bf(float f) {
    unsigned int u = __float_as_uint(f);
    unsigned int r = (u >> 16) & 1u;
    u += 0x7fffu + r;
    return (unsigned short)(u >> 16);
}
__device__ __forceinline__ float ldf(const void* p, long i, int bf) {
    return bf ? bf2f(((const unsigned short*)p)[i]) : ((const float*)p)[i];
}

// ---------------- dtype detection + bkcnt zeroing ----------------
__global__ void detect_k(const unsigned short* xu, const unsigned int* eu, int* flags,
                         int* bkcnt) {
    __shared__ int sbig, snz;
    if (threadIdx.x == 0) { sbig = 0; snz = 0; }
    __syncthreads();
    int t = threadIdx.x;
    bkcnt[t] = 0;
    float f = bf2f(xu[t * 2]);
    if (!(fabsf(f) < 1.0e6f)) atomicOr(&sbig, 1);
    if (eu[t * 2 + 1] != 0u) atomicOr(&snz, 1);
    __syncthreads();
    if (t == 0) {
        flags[0] = sbig ? 0 : 1;
        flags[1] = snz ? 0 : 1;
    }
}

// ---------------- combo2: params-convert (199) || graph bounds (196) || histogram (196) ----
__global__ __launch_bounds__(256) void combo2_k(const int* flags,
                                                const void* w1, const void* b1, const void* w2,
                                                const void* b2, const void* w3, const void* b3,
                                                const void* lw, const void* lb,
                                                unsigned short* wt, float* bfv, float* lwf,
                                                float* lbf, float* pooled,
                                                const unsigned int* eu, int* bkcnt,
                                                const unsigned int* bu, int* starts) {
    __shared__ int sh[256];
    int b = blockIdx.x, tid = threadIdx.x;
    if (b < CVB) {
        int i = b * 256 + tid;
        int bf = flags[0];
        if (i < 16384) pooled[i] = 0.f;
        if (i < 16384) {
            int k = i >> 7, n = i & 127;
            wt[n * 128 + k] = f2bf(ldf(w1, i, bf));
        } else if (i < 32768) {
            int j = i - 16384; int k = j >> 7, n = j & 127;
            wt[16384 + n * 128 + k] = f2bf(ldf(w2, j, bf));
        } else if (i < 49152) {
            int j = i - 32768; int k = j >> 7, n = j & 127;
            wt[32768 + n * 128 + k] = f2bf(ldf(w3, j, bf));
        }
        else if (i < 49280)  bfv[i - 49152] = ldf(b1, i - 49152, bf);
        else if (i < 49408)  bfv[i - 49152] = ldf(b2, i - 49280, bf);
        else if (i < 49536)  bfv[i - 49152] = ldf(b3, i - 49408, bf);
        else if (i < 50816)  lwf[i - 49536] = ldf(lw, i - 49536, bf);
        else if (i < 50826)  lbf[i - 50816] = ldf(lb, i - 50816, bf);
    } else if (b < CVB + NBK) {
        int n = (b - CVB) * 256 + tid;
        if (n < NN) {
            int i64 = flags[1];
            int g = (int)(i64 ? bu[2 * (long)n] : bu[n]);
            g = ((unsigned)g < NG) ? g : 0;
            int gp = -1;
            if (n > 0) {
                gp = (int)(i64 ? bu[2 * (long)(n - 1)] : bu[n - 1]);
                gp = ((unsigned)gp < NG) ? gp : 0;
            }
            for (int gg = gp + 1; gg <= g; gg++) starts[gg] = n;
            if (n == NN - 1) {
                for (int gg = g + 1; gg <= NG; gg++) starts[gg] = NN;
            }
        }
    } else {
        sh[tid] = 0;
        __syncthreads();
        int e0 = (b - CVB - NBK) * CHA;
        int i64 = flags[1];
#pragma unroll
        for (int k = 0; k < 16; k++) {
            int e = e0 + k * 256 + tid;
            if (e < EE) {
                int d = i64 ? (int)((const uint2*)eu)[(long)EE + e].x : (int)eu[EE + e];
                d = ((unsigned)d < NN) ? d : 0;
                atomicAdd(&sh[d >> 8], 1);
            }
        }
        __syncthreads();
        if (sh[tid] > 0) atomicAdd(&bkcnt[tid], sh[tid]);
    }
}

// ---------------- bucket scan: bases + write cursors ----------------
__global__ __launch_bounds__(256) void bkscan_k(const int* bkcnt, int* bkbase, int* bkpos) {
    __shared__ int sb[256];
    int t = threadIdx.x;
    sb[t] = (t < NBUCK) ? bkcnt[t] : 0;
    __syncthreads();
    if (t == 0) {
        int a = 0;
        for (int i = 0; i < NBUCK; i++) { int v = sb[i]; sb[i] = a; a += v; }
        bkbase[NBUCK] = a;
    }
    __syncthreads();
    if (t < NBUCK) { bkbase[t] = sb[t]; bkpos[t] = sb[t]; }
}

// ---------------- mega: GEMM1 (782) || CSR phase A (196) || fold-C build (9) ----------------
__global__ __launch_bounds__(256) void mega_k(const int* flags, const void* x,
                                              const unsigned short* wtp, unsigned short* outp,
                                              const unsigned int* eu, int* bkpos,
                                              unsigned int* ebuck,
                                              const unsigned short* wt3, const float* lwf,
                                              const float* b3, unsigned short* wlc, float* blc) {
    __shared__ __align__(16) char arena[20480];
    int b = blockIdx.x, tid = threadIdx.x;
    if (b < GBK) {
        int wv = tid >> 6, lane = tid & 63;
        int m = lane & 15, quad = lane >> 4;
        int row0 = b * 64;
        int isbf = flags[0];
        bf16x8 af[4];
        if (isbf) {
            int arow = row0 + wv * 16 + m;
            int srow = (arow < NN) ? arow : 0;
            const unsigned short* rp = (const unsigned short*)x + (size_t)srow * 128;
#pragma unroll
            for (int ks = 0; ks < 4; ks++)
                af[ks] = *(const bf16x8*)&rp[ks * 32 + quad * 8];
        } else {
            unsigned short (*As)[136] = (unsigned short(*)[136])arena;
            const float* inf = (const float*)x;
            for (int it = tid; it < 1024; it += 256) {
                int r = it >> 4, seg = it & 15;
                int gr = row0 + r;
                unsigned short tmp[8];
                if (gr < NN) {
#pragma unroll
                    for (int q = 0; q < 8; q++) tmp[q] = f2bf(inf[(size_t)gr * 128 + seg * 8 + q]);
                } else {
#pragma unroll
                    for (int q = 0; q < 8; q++) tmp[q] = 0;
                }
#pragma unroll
                for (int q = 0; q < 8; q++) As[r][seg * 8 + q] = tmp[q];
            }
            __syncthreads();
            int arow = wv * 16 + m;
#pragma unroll
            for (int ks = 0; ks < 4; ks++)
                af[ks] = *(const bf16x8*)&As[arow][ks * 32 + quad * 8];
        }
        int grbase = row0 + wv * 16;
#pragma unroll
        for (int tile = 0; tile < 8; tile++) {
            f32x4 acc = {0.f, 0.f, 0.f, 0.f};
            int n = tile * 16 + m;
#pragma unroll
            for (int ks = 0; ks < 4; ks++) {
                bf16x8 bfr = *(const bf16x8*)&wtp[(size_t)n * 128 + ks * 32 + quad * 8];
                acc = __builtin_amdgcn_mfma_f32_16x16x32_bf16(af[ks], bfr, acc, 0, 0, 0);
            }
#pragma unroll
            for (int r = 0; r < 4; r++) {
                int orow = grbase + quad * 4 + r;
                if (orow < NN) outp[(size_t)orow * 128 + n] = f2bf(acc[r]);
            }
        }
    } else if (b < GBK + NCHA) {
        int* sh_cnt  = (int*)arena;
        int* sh_base = sh_cnt + 256;
        int* sh_ofs  = sh_base + 256;
        int* sh_gb   = sh_ofs + 256;
        unsigned int* staged = (unsigned int*)(arena + 4096);
        int e0 = (b - GBK) * CHA;
        int i64 = flags[1];
        sh_cnt[tid] = 0; sh_ofs[tid] = 0;
        __syncthreads();
        unsigned int pk[16];
#pragma unroll
        for (int k = 0; k < 16; k++) {
            int e = e0 + k * 256 + tid;
            pk[k] = 0xffffffffu;
            if (e < EE) {
                int d, s;
                if (i64) { d = (int)((const uint2*)eu)[(long)EE + e].x; s = (int)((const uint2*)eu)[e].x; }
                else     { d = (int)eu[EE + e]; s = (int)eu[e]; }
                d = ((unsigned)d < NN) ? d : 0;
                s = ((unsigned)s < NN) ? s : 0;
                pk[k] = ((unsigned)s << 16) | ((unsigned)(d & 255) << 8) | (unsigned)(d >> 8);
                atomicAdd(&sh_cnt[d >> 8], 1);
            }
        }
        __syncthreads();
        int v = sh_cnt[tid];
        sh_base[tid] = v;
        __syncthreads();
        for (int off = 1; off < 256; off <<= 1) {
            int add = (tid >= off) ? sh_base[tid - off] : 0;
            __syncthreads();
            sh_base[tid] += add;
            __syncthreads();
        }
        int ex = sh_base[tid] - v;
        __syncthreads();
        sh_base[tid] = ex;
        __syncthreads();
#pragma unroll
        for (int k = 0; k < 16; k++) {
            if (pk[k] != 0xffffffffu) {
                int bk = (int)(pk[k] & 255u);
                int slot = sh_base[bk] + atomicAdd(&sh_ofs[bk], 1);
                staged[slot] = pk[k];
            }
        }
        __syncthreads();
        if (sh_cnt[tid] > 0) sh_gb[tid] = atomicAdd(&bkpos[tid], sh_cnt[tid]);
        __syncthreads();
        int tot = (e0 + CHA <= EE) ? CHA : (EE - e0);
        for (int i = tid; i < tot; i += 256) {
            unsigned int pv = staged[i];
            int bk = (int)(pv & 255u);
            ebuck[sh_gb[bk] + (i - sh_base[bk])] = pv;
        }
    } else if (b < GBK + NCHA + 8) {
        int id = (b - GBK - NCHA) * 256 + tid;   // [0,2048)
        int n = id >> 7, k = id & 127;
        unsigned short h = 0, l = 0;
        if (n < NC) {
            float a0 = 0.f, a1 = 0.f, a2 = 0.f, a3 = 0.f;
            float a4 = 0.f, a5 = 0.f, a6 = 0.f, a7 = 0.f;
            for (int j = 0; j < 128; j += 8) {
                a0 += bf2f(wt3[(j + 0) * 128 + k]) * lwf[(j + 0) * NC + n];
                a1 += bf2f(wt3[(j + 1) * 128 + k]) * lwf[(j + 1) * NC + n];
                a2 += bf2f(wt3[(j + 2) * 128 + k]) * lwf[(j + 2) * NC + n];
                a3 += bf2f(wt3[(j + 3) * 128 + k]) * lwf[(j + 3) * NC + n];
                a4 += bf2f(wt3[(j + 4) * 128 + k]) * lwf[(j + 4) * NC + n];
                a5 += bf2f(wt3[(j + 5) * 128 + k]) * lwf[(j + 5) * NC + n];
                a6 += bf2f(wt3[(j + 6) * 128 + k]) * lwf[(j + 6) * NC + n];
                a7 += bf2f(wt3[(j + 7) * 128 + k]) * lwf[(j + 7) * NC + n];
            }
            float acc = ((a0 + a1) + (a2 + a3)) + ((a4 + a5) + (a6 + a7));
            h = f2bf(acc);
            l = f2bf(acc - bf2f(h));
        }
        wlc[id] = h;
        wlc[2048 + id] = l;
    } else {
        if (tid < 16) {
            float acc = 0.f;
            if (tid < NC) {
                float a0 = 0.f, a1 = 0.f, a2 = 0.f, a3 = 0.f;
                for (int j = 0; j < 128; j += 4) {
                    a0 += b3[j + 0] * lwf[(j + 0) * NC + tid];
                    a1 += b3[j + 1] * lwf[(j + 1) * NC + tid];
                    a2 += b3[j + 2] * lwf[(j + 2) * NC + tid];
                    a3 += b3[j + 3] * lwf[(j + 3) * NC + tid];
                }
                acc = (a0 + a1) + (a2 + a3);
            }
            blc[tid] = acc;
        }
    }
}

// ---------------- CSR phase B: per-bucket LDS sort -> rowptr + dinv + colsrc ----------
__global__ __launch_bounds__(256) void csrB_k(const unsigned int* ebuck, const int* bkbase,
                                              int* rowptr, float* dinv, unsigned short* colsrc) {
    __shared__ int sh_cnt[256];
    __shared__ int sh_base[256];
    __shared__ int sh_ofs[256];
    __shared__ unsigned short ssrc[CAPB];
    int b = blockIdx.x, tid = threadIdx.x;
    int j0 = bkbase[b];
    int cnt = bkbase[b + 1] - j0;
    sh_cnt[tid] = 0; sh_ofs[tid] = 0;
    __syncthreads();
    for (int i = tid; i < cnt; i += 256)
        atomicAdd(&sh_cnt[(ebuck[j0 + i] >> 8) & 255u], 1);
    __syncthreads();
    int v = sh_cnt[tid];
    sh_base[tid] = v;
    __syncthreads();
    for (int off = 1; off < 256; off <<= 1) {
        int add = (tid >= off) ? sh_base[tid - off] : 0;
        __syncthreads();
        sh_base[tid] += add;
        __syncthreads();
    }
    int ex = sh_base[tid] - v;
    __syncthreads();
    sh_base[tid] = ex;
    __syncthreads();
    int n = (b << 8) + tid;
    if (n < NN) {
        rowptr[n] = j0 + ex;
        dinv[n] = rsqrtf((float)(v + 1));
    }
    if (b == NBUCK - 1 && tid == 0) rowptr[NN] = bkbase[NBUCK];
    if (cnt <= CAPB) {
        for (int i = tid; i < cnt; i += 256) {
            unsigned int pv = ebuck[j0 + i];
            int dl = (int)((pv >> 8) & 255u);
            int slot = sh_base[dl] + atomicAdd(&sh_ofs[dl], 1);
            ssrc[slot] = (unsigned short)(pv >> 16);
        }
        __syncthreads();
        for (int i = tid; i < cnt; i += 256)
            colsrc[j0 + i] = ssrc[i];
    } else {
        for (int i = tid; i < cnt; i += 256) {
            unsigned int pv = ebuck[j0 + i];
            int dl = (int)((pv >> 8) & 255u);
            int slot = sh_base[dl] + atomicAdd(&sh_ofs[dl], 1);
            colsrc[j0 + slot] = (unsigned short)(pv >> 16);
        }
    }
}

// ---------------- wnorm: coalesced post-pass, wnorm[e] = dinv[colsrc[e]] ----------------
__global__ __launch_bounds__(256) void wnorm_k(const unsigned short* colsrc, const float* dinv,
                                               float* wnorm) {
    int i = blockIdx.x * 256 + threadIdx.x;
    if (i >= EE / 8) return;
    uint4 c = ((const uint4*)colsrc)[i];
    unsigned int cs[4] = {c.x, c.y, c.z, c.w};
    float w[8];
#pragma unroll
    for (int q = 0; q < 4; q++) {
        w[2 * q]     = dinv[cs[q] & 0xffffu];
        w[2 * q + 1] = dinv[cs[q] >> 16];
    }
    ((float4*)wnorm)[2 * i]     = make_float4(w[0], w[1], w[2], w[3]);
    ((float4*)wnorm)[2 * i + 1] = make_float4(w[4], w[5], w[6], w[7]);
}

// ---------------- per-node aggregation: padded 16-wide batches, uniform ILP ----------------
__device__ __forceinline__ void agg_node2(const unsigned short* t, int n, int lane,
                                          const float* bias, const int* rowptr,
                                          const unsigned short* colsrc, const float* wnorm,
                                          const float* dinv, float& axo, float& ayo) {
    float dn = dinv[n];
    unsigned int sf = ((const unsigned int*)(t + (size_t)n * 128))[lane];
    float sx0 = dn * bf2f((unsigned short)(sf & 0xffffu));
    float sy0 = dn * bf2f((unsigned short)(sf >> 16));
    float sx1 = 0.f, sy1 = 0.f;
    int j0 = rowptr[n];
    int cnt = rowptr[n + 1] - j0;
    for (int e0 = 0; e0 < cnt; e0 += 64) {
        int m = cnt - e0; if (m > 64) m = 64;
        int idx = 0; float w = 0.f;          // pad lanes: idx=0 (row 0, L1-hot), w=0 (adds 0)
        if (lane < m) {
            idx = (int)colsrc[j0 + e0 + lane];
            idx = ((unsigned)idx < NN) ? idx : 0;
            w = wnorm[j0 + e0 + lane];
        }
        for (int e = 0; e < m; e += 16) {
            int s[16]; float wr[16]; unsigned int v[16];
#pragma unroll
            for (int i = 0; i < 16; i++) { s[i] = __shfl(idx, e + i); wr[i] = __shfl(w, e + i); }
#pragma unroll
            for (int i = 0; i < 16; i++)
                v[i] = ((const unsigned int*)(t + (size_t)s[i] * 128))[lane];
#pragma unroll
            for (int i = 0; i < 16; i++) {
                float lo = bf2f((unsigned short)(v[i] & 0xffffu));
                float hi = bf2f((unsigned short)(v[i] >> 16));
                if (i & 1) { sx1 += wr[i] * lo; sy1 += wr[i] * hi; }
                else       { sx0 += wr[i] * lo; sy0 += wr[i] * hi; }
            }
        }
    }
    axo = bias[2 * lane]     + dn * (sx0 + sx1);
    ayo = bias[2 * lane + 1] + dn * (sy0 + sy1);
}

// ---------------- fused agg(+relu,bias) -> 16x128 @ 128x128 MFMA GEMM ----------------
// 16 waves/block; wave w aggregates node blk*16+w IN PARALLEL (one wave per node — the
// proven TLP structure), then one barrier, then waves 0-7 each compute one 16-col N-tile.
// NN = 16*3125 exactly -> no partial blocks.
__global__ __launch_bounds__(1024) void aggemm2_k(const unsigned short* tin,
                                                  const unsigned short* wtp, const float* bias,
                                                  const int* rowptr, const unsigned short* colsrc,
                                                  const float* wnorm, const float* dinv,
                                                  unsigned short* outp) {
    __shared__ unsigned short As[16][136];
    int tid = threadIdx.x;
    int wv = tid >> 6, lane = tid & 63;
    int n = blockIdx.x * 16 + wv;
    float ax, ay;
    agg_node2(tin, n, lane, bias, rowptr, colsrc, wnorm, dinv, ax, ay);
    ax = fmaxf(ax, 0.f); ay = fmaxf(ay, 0.f);   // relu
    ((unsigned int*)&As[wv][0])[lane] = (unsigned int)f2bf(ax) | ((unsigned int)f2bf(ay) << 16);
    __syncthreads();
    if (wv < 8) {
        int m = lane & 15, quad = lane >> 4;
        bf16x8 af[4];
#pragma unroll
        for (int ks = 0; ks < 4; ks++)
            af[ks] = *(const bf16x8*)&As[m][ks * 32 + quad * 8];
        f32x4 acc = {0.f, 0.f, 0.f, 0.f};
        int nc = wv * 16 + m;
#pragma unroll
        for (int ks = 0; ks < 4; ks++) {
            bf16x8 bfr = *(const bf16x8*)&wtp[(size_t)nc * 128 + ks * 32 + quad * 8];
            acc = __builtin_amdgcn_mfma_f32_16x16x32_bf16(af[ks], bfr, acc, 0, 0, 0);
        }
        int grbase = blockIdx.x * 16;
#pragma unroll
        for (int r = 0; r < 4; r++) {
            int orow = grbase + quad * 4 + r;
            outp[(size_t)orow * 128 + nc] = f2bf(acc[r]);
        }
    }
}

// ---------------- fused agg(+relu,b2) -> 16x128 @ C(128->16, split bf16) -> [NN][16] -------
__global__ __launch_bounds__(1024) void aggemm3_k(const unsigned short* tin,
                                                  const unsigned short* wlc, const float* bias,
                                                  const int* rowptr, const unsigned short* colsrc,
                                                  const float* wnorm, const float* dinv,
                                                  unsigned short* out16) {
    __shared__ unsigned short As[16][136];
    int tid = threadIdx.x;
    int wv = tid >> 6, lane = tid & 63;
    int n = blockIdx.x * 16 + wv;
    float ax, ay;
    agg_node2(tin, n, lane, bias, rowptr, colsrc, wnorm, dinv, ax, ay);
    ax = fmaxf(ax, 0.f); ay = fmaxf(ay, 0.f);   // relu
    ((unsigned int*)&As[wv][0])[lane] = (unsigned int)f2bf(ax) | ((unsigned int)f2bf(ay) << 16);
    __syncthreads();
    if (wv == 0) {
        int m = lane & 15, quad = lane >> 4;
        f32x4 acc = {0.f, 0.f, 0.f, 0.f};
#pragma unroll
        for (int ks = 0; ks < 4; ks++) {
            bf16x8 af = *(const bf16x8*)&As[m][ks * 32 + quad * 8];
            bf16x8 bh = *(const bf16x8*)&wlc[m * 128 + ks * 32 + quad * 8];
            bf16x8 bl = *(const bf16x8*)&wlc[2048 + m * 128 + ks * 32 + quad * 8];
            acc = __builtin_amdgcn_mfma_f32_16x16x32_bf16(af, bh, acc, 0, 0, 0);
            acc = __builtin_amdgcn_mfma_f32_16x16x32_bf16(af, bl, acc, 0, 0, 0);
        }
        int grbase = blockIdx.x * 16;
#pragma unroll
        for (int r = 0; r < 4; r++) {
            int orow = grbase + quad * 4 + r;
            out16[(size_t)orow * 16 + m] = f2bf(acc[r]);
        }
    }
}

// ---------------- final agg on 16-wide rows + per-graph f32 pool ----------------
__global__ __launch_bounds__(256) void aggpool10_k(const unsigned short* t16, const int* rowptr,
                                                   const unsigned short* colsrc, const float* wnorm,
                                                   const float* dinv, const unsigned int* bu,
                                                   const int* flags, float* pooled) {
    __shared__ float sacc[4][16];
    __shared__ int sg[4];
    int tid = threadIdx.x, wv = tid >> 6, lane = tid & 63;
    int n = blockIdx.x * 4 + wv;
    int slot = lane >> 3, fi = lane & 7;
    int i64 = flags[1];
    int g = -1;
    float ax = 0.f, ay = 0.f, bx = 0.f, by = 0.f;
    if (n < NN) {
        g = (int)(i64 ? bu[2 * (size_t)n] : bu[n]);
        g = ((unsigned)g < NG) ? g : 0;
        float dn = dinv[n];
        int j0 = rowptr[n];
        int cnt = rowptr[n + 1] - j0;
        const unsigned int* tp = (const unsigned int*)t16;
        for (int e0 = 0; e0 < cnt; e0 += 64) {
            int mm = cnt - e0; if (mm > 64) mm = 64;
            int idx = 0; float w = 0.f;
            if (lane < mm) {
                idx = (int)colsrc[j0 + e0 + lane];
                idx = ((unsigned)idx < NN) ? idx : 0;
                w = wnorm[j0 + e0 + lane];
            }
            for (int e = 0; e < mm; e += 16) {
                int s0 = __shfl(idx, e + slot);      float w0 = __shfl(w, e + slot);
                int s1 = __shfl(idx, e + 8 + slot);  float w1 = __shfl(w, e + 8 + slot);
                unsigned int v0 = tp[(size_t)s0 * 8 + fi];
                unsigned int v1 = tp[(size_t)s1 * 8 + fi];
                ax += w0 * bf2f((unsigned short)(v0 & 0xffffu));
                ay += w0 * bf2f((unsigned short)(v0 >> 16));
                bx += w1 * bf2f((unsigned short)(v1 & 0xffffu));
                by += w1 * bf2f((unsigned short)(v1 >> 16));
            }
        }
        ax += bx; ay += by;
        ax += __shfl_xor(ax, 8);  ay += __shfl_xor(ay, 8);
        ax += __shfl_xor(ax, 16); ay += __shfl_xor(ay, 16);
        ax += __shfl_xor(ax, 32); ay += __shfl_xor(ay, 32);
        unsigned int sv = tp[(size_t)n * 8 + fi];
        float dn2 = dn * dn;
        ax = ax * dn + dn2 * bf2f((unsigned short)(sv & 0xffffu));
        ay = ay * dn + dn2 * bf2f((unsigned short)(sv >> 16));
    }
    if (slot == 0) { sacc[wv][2 * fi] = ax; sacc[wv][2 * fi + 1] = ay; }
    if (lane == 0) sg[wv] = g;
    __syncthreads();
    if (tid < 16) {
        float acc = 0.f; int curg = -1;
        for (int w2 = 0; w2 < 4; w2++) {
            int gg = sg[w2];
            if (gg < 0) continue;
            if (gg == curg) acc += sacc[w2][tid];
            else {
                if (curg >= 0) atomicAdd(&pooled[curg * 16 + tid], acc);
                curg = gg; acc = sacc[w2][tid];
            }
        }
        if (curg >= 0) atomicAdd(&pooled[curg * 16 + tid], acc);
    }
}

// ---------------- head: out[g][c] = pooled/cnt + b3@lin + lin_b ----------------
__global__ __launch_bounds__(64) void head10_k(const float* pooled, const int* starts,
                                               const float* blc, const float* lbf,
                                               void* outp, const int* flags) {
    int g = blockIdx.x, t = threadIdx.x;
    if (t >= NC) return;
    int c = starts[g + 1] - starts[g];
    float o;
    if (c > 0) o = pooled[g * 16 + t] / (float)c + blc[t] + lbf[t];
    else       o = lbf[t];   // empty graph: pooled=0 in reference -> out = lin_b
    if (flags[0]) ((unsigned short*)outp)[g * NC + t] = f2bf(o);
    else          ((float*)outp)[g * NC + t] = o;
}

extern "C" void kernel_launch(void* const* d_in, const int* in_sizes, int n_in,
                              void* d_out, int out_size, void* d_ws, size_t ws_size,
                              hipStream_t stream) {
    char* ws = (char*)d_ws;
    size_t off = 0;
    auto alloc = [&](size_t bytes) { size_t o = off; off = (off + bytes + 255) & ~(size_t)255; return o; };

    int*   flags  = (int*)(ws + alloc(32 * 4));
    int*   rowptr = (int*)(ws + alloc((size_t)(NN + 1) * 4));
    int*   starts = (int*)(ws + alloc((size_t)(NG + 1) * 4));
    int*   bkcnt  = (int*)(ws + alloc((size_t)256 * 4));
    int*   bkbase = (int*)(ws + alloc((size_t)512 * 4));
    int*   bkpos  = (int*)(ws + alloc((size_t)256 * 4));
    unsigned int* ebuck = (unsigned int*)(ws + alloc((size_t)EE * 4));
    unsigned short* colsrc = (unsigned short*)(ws + alloc((size_t)EE * 2));
    float* wnorm  = (float*)(ws + alloc((size_t)EE * 4));
    float* dinv   = (float*)(ws + alloc((size_t)NN * 4));
    unsigned short* wt  = (unsigned short*)(ws + alloc((size_t)3 * 16384 * 2));
    unsigned short* wlc = (unsigned short*)(ws + alloc((size_t)2 * 2048 * 2));
    float* blc    = (float*)(ws + alloc((size_t)16 * 4));
    float* bfv    = (float*)(ws + alloc((size_t)3 * 128 * 4));
    float* lwf    = (float*)(ws + alloc((size_t)1280 * 4));
    float* lbf    = (float*)(ws + alloc((size_t)16 * 4));
    float* pooled = (float*)(ws + alloc((size_t)NG * 128 * 4));
    unsigned short* tbuf = (unsigned short*)(ws + alloc((size_t)NN * 128 * 2));
    unsigned short* hbuf = (unsigned short*)(ws + alloc((size_t)NN * 128 * 2));

    const void* x = d_in[0];
    const unsigned int* eu = (const unsigned int*)d_in[1];
    const unsigned int* bu = (const unsigned int*)d_in[2];

    detect_k<<<1, 256, 0, stream>>>((const unsigned short*)x, eu, flags, bkcnt);

    // params-convert || graph bounds || bucket histogram
    combo2_k<<<CVB + NBK + NCHA, 256, 0, stream>>>(flags, d_in[3], d_in[4], d_in[5], d_in[6],
                                                   d_in[7], d_in[8], d_in[9], d_in[10],
                                                   wt, bfv, lwf, lbf, pooled,
                                                   eu, bkcnt, bu, starts);

    bkscan_k<<<1, 256, 0, stream>>>(bkcnt, bkbase, bkpos);

    // GEMM1 || CSR phase A || folded-weight build
    mega_k<<<GBK + NCHA + 9, 256, 0, stream>>>(flags, x, wt, tbuf, eu, bkpos, ebuck,
                                               wt + 32768, lwf, bfv + 256, wlc, blc);

    csrB_k<<<NBUCK, 256, 0, stream>>>(ebuck, bkbase, rowptr, dinv, colsrc);
    wnorm_k<<<(EE / 8 + 255) / 256, 256, 0, stream>>>(colsrc, dinv, wnorm);

    // fused: agg1(+relu,b1) + GEMM(W2)  ->  hbuf
    aggemm2_k<<<FBK, 1024, 0, stream>>>(tbuf, wt + 16384, bfv, rowptr, colsrc, wnorm, dinv, hbuf);
    // fused: agg2(+relu,b2) + GEMM(C=W3*lin)  ->  tbuf[NN][16]
    aggemm3_k<<<FBK, 1024, 0, stream>>>(hbuf, wlc, bfv + 128, rowptr, colsrc, wnorm, dinv, tbuf);

    aggpool10_k<<<(NN + 3) / 4, 256, 0, stream>>>(tbuf, rowptr, colsrc, wnorm, dinv,
                                                  bu, flags, pooled);

    head10_k<<<NG, 64, 0, stream>>>(pooled, starts, blc, lbf, d_out, flags);
}

// Round 14
// 255.497 us; speedup vs baseline: 1.0406x; 1.0406x over previous
//
#include <hip/hip_runtime.h>
#include <hip/hip_bf16.h>

#define NN 50000
#define EE 800000
#define FD 128
#define NG 128
#define NC 10
#define GBK 782   // (NN+63)/64
#define NBK 196   // (NN+255)/256
#define NBUCK 196 // dst buckets of 256 nodes
#define CHA 4096  // edges per chunk
#define NCHA 196  // ceil(EE/CHA)
#define CAPB 8192 // phase-B LDS staging capacity
#define CVB 199   // cvt blocks

typedef __attribute__((ext_vector_type(8))) short bf16x8;
typedef __attribute__((ext_vector_type(4))) float f32x4;

__device__ __forceinline__ float bf2f(unsigned short u) {
    return __uint_as_float(((unsigned int)u) << 16);
}
__device__ __forceinline__ unsigned short f2bf(float f) {
    unsigned int u = __float_as_uint(f);
    unsigned int r = (u >> 16) & 1u;
    u += 0x7fffu + r;
    return (unsigned short)(u >> 16);
}
__device__ __forceinline__ float ldf(const void* p, long i, int bf) {
    return bf ? bf2f(((const unsigned short*)p)[i]) : ((const float*)p)[i];
}

// ---------------- dtype detection + bkcnt zeroing ----------------
__global__ void detect_k(const unsigned short* xu, const unsigned int* eu, int* flags,
                         int* bkcnt) {
    __shared__ int sbig, snz;
    if (threadIdx.x == 0) { sbig = 0; snz = 0; }
    __syncthreads();
    int t = threadIdx.x;
    bkcnt[t] = 0;
    float f = bf2f(xu[t * 2]);
    if (!(fabsf(f) < 1.0e6f)) atomicOr(&sbig, 1);
    if (eu[t * 2 + 1] != 0u) atomicOr(&snz, 1);
    __syncthreads();
    if (t == 0) {
        flags[0] = sbig ? 0 : 1;
        flags[1] = snz ? 0 : 1;
    }
}

// ---------------- combo2: params-convert (199) || graph bounds (196) || histogram (196) ----
__global__ __launch_bounds__(256) void combo2_k(const int* flags,
                                                const void* w1, const void* b1, const void* w2,
                                                const void* b2, const void* w3, const void* b3,
                                                const void* lw, const void* lb,
                                                unsigned short* wt, float* bfv, float* lwf,
                                                float* lbf, float* pooled,
                                                const unsigned int* eu, int* bkcnt,
                                                const unsigned int* bu, int* starts) {
    __shared__ int sh[256];
    int b = blockIdx.x, tid = threadIdx.x;
    if (b < CVB) {
        int i = b * 256 + tid;
        int bf = flags[0];
        if (i < 16384) pooled[i] = 0.f;
        if (i < 16384) {
            int k = i >> 7, n = i & 127;
            wt[n * 128 + k] = f2bf(ldf(w1, i, bf));
        } else if (i < 32768) {
            int j = i - 16384; int k = j >> 7, n = j & 127;
            wt[16384 + n * 128 + k] = f2bf(ldf(w2, j, bf));
        } else if (i < 49152) {
            int j = i - 32768; int k = j >> 7, n = j & 127;
            wt[32768 + n * 128 + k] = f2bf(ldf(w3, j, bf));
        }
        else if (i < 49280)  bfv[i - 49152] = ldf(b1, i - 49152, bf);
        else if (i < 49408)  bfv[i - 49152] = ldf(b2, i - 49280, bf);
        else if (i < 49536)  bfv[i - 49152] = ldf(b3, i - 49408, bf);
        else if (i < 50816)  lwf[i - 49536] = ldf(lw, i - 49536, bf);
        else if (i < 50826)  lbf[i - 50816] = ldf(lb, i - 50816, bf);
    } else if (b < CVB + NBK) {
        int n = (b - CVB) * 256 + tid;
        if (n < NN) {
            int i64 = flags[1];
            int g = (int)(i64 ? bu[2 * (long)n] : bu[n]);
            g = ((unsigned)g < NG) ? g : 0;
            int gp = -1;
            if (n > 0) {
                gp = (int)(i64 ? bu[2 * (long)(n - 1)] : bu[n - 1]);
                gp = ((unsigned)gp < NG) ? gp : 0;
            }
            for (int gg = gp + 1; gg <= g; gg++) starts[gg] = n;
            if (n == NN - 1) {
                for (int gg = g + 1; gg <= NG; gg++) starts[gg] = NN;
            }
        }
    } else {
        sh[tid] = 0;
        __syncthreads();
        int e0 = (b - CVB - NBK) * CHA;
        int i64 = flags[1];
#pragma unroll
        for (int k = 0; k < 16; k++) {
            int e = e0 + k * 256 + tid;
            if (e < EE) {
                int d = i64 ? (int)((const uint2*)eu)[(long)EE + e].x : (int)eu[EE + e];
                d = ((unsigned)d < NN) ? d : 0;
                atomicAdd(&sh[d >> 8], 1);
            }
        }
        __syncthreads();
        if (sh[tid] > 0) atomicAdd(&bkcnt[tid], sh[tid]);
    }
}

// ---------------- bucket scan: bases + write cursors ----------------
__global__ __launch_bounds__(256) void bkscan_k(const int* bkcnt, int* bkbase, int* bkpos) {
    __shared__ int sb[256];
    int t = threadIdx.x;
    sb[t] = (t < NBUCK) ? bkcnt[t] : 0;
    __syncthreads();
    if (t == 0) {
        int a = 0;
        for (int i = 0; i < NBUCK; i++) { int v = sb[i]; sb[i] = a; a += v; }
        bkbase[NBUCK] = a;
    }
    __syncthreads();
    if (t < NBUCK) { bkbase[t] = sb[t]; bkpos[t] = sb[t]; }
}

// ---------------- mega: GEMM1 (782) || CSR phase A (196) || fold-C build (9) ----------------
// LDS arena manually unioned: gemm1-f32 path needs 17408 B, csrA needs 20480 B.
__global__ __launch_bounds__(256) void mega_k(const int* flags, const void* x,
                                              const unsigned short* wtp, unsigned short* outp,
                                              const unsigned int* eu, int* bkpos,
                                              unsigned int* ebuck,
                                              const unsigned short* wt3, const float* lwf,
                                              const float* b3, unsigned short* wlc, float* blc) {
    __shared__ __align__(16) char arena[20480];
    int b = blockIdx.x, tid = threadIdx.x;
    if (b < GBK) {
        int wv = tid >> 6, lane = tid & 63;
        int m = lane & 15, quad = lane >> 4;
        int row0 = b * 64;
        int isbf = flags[0];
        bf16x8 af[4];
        if (isbf) {
            // bf16 fast path: A-fragments straight from global (no LDS, no barriers)
            int arow = row0 + wv * 16 + m;
            int srow = (arow < NN) ? arow : 0;
            const unsigned short* rp = (const unsigned short*)x + (size_t)srow * 128;
#pragma unroll
            for (int ks = 0; ks < 4; ks++)
                af[ks] = *(const bf16x8*)&rp[ks * 32 + quad * 8];
        } else {
            unsigned short (*As)[136] = (unsigned short(*)[136])arena;
            const float* inf = (const float*)x;
            for (int it = tid; it < 1024; it += 256) {
                int r = it >> 4, seg = it & 15;
                int gr = row0 + r;
                unsigned short tmp[8];
                if (gr < NN) {
#pragma unroll
                    for (int q = 0; q < 8; q++) tmp[q] = f2bf(inf[(size_t)gr * 128 + seg * 8 + q]);
                } else {
#pragma unroll
                    for (int q = 0; q < 8; q++) tmp[q] = 0;
                }
#pragma unroll
                for (int q = 0; q < 8; q++) As[r][seg * 8 + q] = tmp[q];
            }
            __syncthreads();
            int arow = wv * 16 + m;
#pragma unroll
            for (int ks = 0; ks < 4; ks++)
                af[ks] = *(const bf16x8*)&As[arow][ks * 32 + quad * 8];
        }
        int grbase = row0 + wv * 16;
#pragma unroll
        for (int tile = 0; tile < 8; tile++) {
            f32x4 acc = {0.f, 0.f, 0.f, 0.f};
            int n = tile * 16 + m;
#pragma unroll
            for (int ks = 0; ks < 4; ks++) {
                bf16x8 bfr = *(const bf16x8*)&wtp[(size_t)n * 128 + ks * 32 + quad * 8];
                acc = __builtin_amdgcn_mfma_f32_16x16x32_bf16(af[ks], bfr, acc, 0, 0, 0);
            }
#pragma unroll
            for (int r = 0; r < 4; r++) {
                int orow = grbase + quad * 4 + r;
                if (orow < NN) outp[(size_t)orow * 128 + n] = f2bf(acc[r]);
            }
        }
    } else if (b < GBK + NCHA) {
        // ---- CSR phase A: pack src[31:16] | dstlocal[15:8] | bucket[7:0] ----
        int* sh_cnt  = (int*)arena;
        int* sh_base = sh_cnt + 256;
        int* sh_ofs  = sh_base + 256;
        int* sh_gb   = sh_ofs + 256;
        unsigned int* staged = (unsigned int*)(arena + 4096);
        int e0 = (b - GBK) * CHA;
        int i64 = flags[1];
        sh_cnt[tid] = 0; sh_ofs[tid] = 0;
        __syncthreads();
        unsigned int pk[16];
#pragma unroll
        for (int k = 0; k < 16; k++) {
            int e = e0 + k * 256 + tid;
            pk[k] = 0xffffffffu;
            if (e < EE) {
                int d, s;
                if (i64) { d = (int)((const uint2*)eu)[(long)EE + e].x; s = (int)((const uint2*)eu)[e].x; }
                else     { d = (int)eu[EE + e]; s = (int)eu[e]; }
                d = ((unsigned)d < NN) ? d : 0;
                s = ((unsigned)s < NN) ? s : 0;
                pk[k] = ((unsigned)s << 16) | ((unsigned)(d & 255) << 8) | (unsigned)(d >> 8);
                atomicAdd(&sh_cnt[d >> 8], 1);
            }
        }
        __syncthreads();
        int v = sh_cnt[tid];
        sh_base[tid] = v;
        __syncthreads();
        for (int off = 1; off < 256; off <<= 1) {
            int add = (tid >= off) ? sh_base[tid - off] : 0;
            __syncthreads();
            sh_base[tid] += add;
            __syncthreads();
        }
        int ex = sh_base[tid] - v;
        __syncthreads();
        sh_base[tid] = ex;
        __syncthreads();
#pragma unroll
        for (int k = 0; k < 16; k++) {
            if (pk[k] != 0xffffffffu) {
                int bk = (int)(pk[k] & 255u);
                int slot = sh_base[bk] + atomicAdd(&sh_ofs[bk], 1);
                staged[slot] = pk[k];
            }
        }
        __syncthreads();
        if (sh_cnt[tid] > 0) sh_gb[tid] = atomicAdd(&bkpos[tid], sh_cnt[tid]);
        __syncthreads();
        int tot = (e0 + CHA <= EE) ? CHA : (EE - e0);
        for (int i = tid; i < tot; i += 256) {
            unsigned int pv = staged[i];
            int bk = (int)(pv & 255u);
            ebuck[sh_gb[bk] + (i - sh_base[bk])] = pv;
        }
    } else if (b < GBK + NCHA + 8) {
        // C[k][n] = sum_j W3[k][j]*lin[j][n] (ILP-8), split bf16 hi+lo
        int id = (b - GBK - NCHA) * 256 + tid;   // [0,2048)
        int n = id >> 7, k = id & 127;
        unsigned short h = 0, l = 0;
        if (n < NC) {
            float a0 = 0.f, a1 = 0.f, a2 = 0.f, a3 = 0.f;
            float a4 = 0.f, a5 = 0.f, a6 = 0.f, a7 = 0.f;
            for (int j = 0; j < 128; j += 8) {
                a0 += bf2f(wt3[(j + 0) * 128 + k]) * lwf[(j + 0) * NC + n];
                a1 += bf2f(wt3[(j + 1) * 128 + k]) * lwf[(j + 1) * NC + n];
                a2 += bf2f(wt3[(j + 2) * 128 + k]) * lwf[(j + 2) * NC + n];
                a3 += bf2f(wt3[(j + 3) * 128 + k]) * lwf[(j + 3) * NC + n];
                a4 += bf2f(wt3[(j + 4) * 128 + k]) * lwf[(j + 4) * NC + n];
                a5 += bf2f(wt3[(j + 5) * 128 + k]) * lwf[(j + 5) * NC + n];
                a6 += bf2f(wt3[(j + 6) * 128 + k]) * lwf[(j + 6) * NC + n];
                a7 += bf2f(wt3[(j + 7) * 128 + k]) * lwf[(j + 7) * NC + n];
            }
            float acc = ((a0 + a1) + (a2 + a3)) + ((a4 + a5) + (a6 + a7));
            h = f2bf(acc);
            l = f2bf(acc - bf2f(h));
        }
        wlc[id] = h;
        wlc[2048 + id] = l;
    } else {
        if (tid < 16) {
            float acc = 0.f;
            if (tid < NC) {
                float a0 = 0.f, a1 = 0.f, a2 = 0.f, a3 = 0.f;
                for (int j = 0; j < 128; j += 4) {
                    a0 += b3[j + 0] * lwf[(j + 0) * NC + tid];
                    a1 += b3[j + 1] * lwf[(j + 1) * NC + tid];
                    a2 += b3[j + 2] * lwf[(j + 2) * NC + tid];
                    a3 += b3[j + 3] * lwf[(j + 3) * NC + tid];
                }
                acc = (a0 + a1) + (a2 + a3);
            }
            blc[tid] = acc;
        }
    }
}

// ---------------- CSR phase B: per-bucket LDS sort -> rowptr + dinv + colsrc ----------
__global__ __launch_bounds__(256) void csrB_k(const unsigned int* ebuck, const int* bkbase,
                                              int* rowptr, float* dinv, unsigned short* colsrc) {
    __shared__ int sh_cnt[256];
    __shared__ int sh_base[256];
    __shared__ int sh_ofs[256];
    __shared__ unsigned short ssrc[CAPB];
    int b = blockIdx.x, tid = threadIdx.x;
    int j0 = bkbase[b];
    int cnt = bkbase[b + 1] - j0;
    sh_cnt[tid] = 0; sh_ofs[tid] = 0;
    __syncthreads();
    for (int i = tid; i < cnt; i += 256)
        atomicAdd(&sh_cnt[(ebuck[j0 + i] >> 8) & 255u], 1);
    __syncthreads();
    int v = sh_cnt[tid];
    sh_base[tid] = v;
    __syncthreads();
    for (int off = 1; off < 256; off <<= 1) {
        int add = (tid >= off) ? sh_base[tid - off] : 0;
        __syncthreads();
        sh_base[tid] += add;
        __syncthreads();
    }
    int ex = sh_base[tid] - v;
    __syncthreads();
    sh_base[tid] = ex;
    __syncthreads();
    int n = (b << 8) + tid;
    if (n < NN) {
        rowptr[n] = j0 + ex;
        dinv[n] = rsqrtf((float)(v + 1));
    }
    if (b == NBUCK - 1 && tid == 0) rowptr[NN] = bkbase[NBUCK];
    if (cnt <= CAPB) {
        for (int i = tid; i < cnt; i += 256) {
            unsigned int pv = ebuck[j0 + i];
            int dl = (int)((pv >> 8) & 255u);
            int slot = sh_base[dl] + atomicAdd(&sh_ofs[dl], 1);
            ssrc[slot] = (unsigned short)(pv >> 16);
        }
        __syncthreads();
        for (int i = tid; i < cnt; i += 256)
            colsrc[j0 + i] = ssrc[i];
    } else {
        for (int i = tid; i < cnt; i += 256) {
            unsigned int pv = ebuck[j0 + i];
            int dl = (int)((pv >> 8) & 255u);
            int slot = sh_base[dl] + atomicAdd(&sh_ofs[dl], 1);
            colsrc[j0 + slot] = (unsigned short)(pv >> 16);
        }
    }
}

// ---------------- wnorm: coalesced post-pass, wnorm[e] = dinv[colsrc[e]] ----------------
__global__ __launch_bounds__(256) void wnorm_k(const unsigned short* colsrc, const float* dinv,
                                               float* wnorm) {
    int i = blockIdx.x * 256 + threadIdx.x;
    if (i >= EE / 8) return;
    uint4 c = ((const uint4*)colsrc)[i];
    unsigned int cs[4] = {c.x, c.y, c.z, c.w};
    float w[8];
#pragma unroll
    for (int q = 0; q < 4; q++) {
        w[2 * q]     = dinv[cs[q] & 0xffffu];
        w[2 * q + 1] = dinv[cs[q] >> 16];
    }
    ((float4*)wnorm)[2 * i]     = make_float4(w[0], w[1], w[2], w[3]);
    ((float4*)wnorm)[2 * i + 1] = make_float4(w[4], w[5], w[6], w[7]);
}

// ---------------- per-node aggregation: padded 16-wide batches, uniform ILP ----------------
__device__ __forceinline__ void agg_node2(const unsigned short* t, int n, int lane,
                                          const float* bias, const int* rowptr,
                                          const unsigned short* colsrc, const float* wnorm,
                                          const float* dinv, float& axo, float& ayo) {
    float dn = dinv[n];
    unsigned int sf = ((const unsigned int*)(t + (size_t)n * 128))[lane];
    float sx0 = dn * bf2f((unsigned short)(sf & 0xffffu));
    float sy0 = dn * bf2f((unsigned short)(sf >> 16));
    float sx1 = 0.f, sy1 = 0.f;
    int j0 = rowptr[n];
    int cnt = rowptr[n + 1] - j0;
    for (int e0 = 0; e0 < cnt; e0 += 64) {
        int m = cnt - e0; if (m > 64) m = 64;
        int idx = 0; float w = 0.f;          // pad lanes: idx=0 (row 0, L1-hot), w=0 (adds 0)
        if (lane < m) {
            idx = (int)colsrc[j0 + e0 + lane];
            idx = ((unsigned)idx < NN) ? idx : 0;
            w = wnorm[j0 + e0 + lane];
        }
        for (int e = 0; e < m; e += 16) {
            int s[16]; float wr[16]; unsigned int v[16];
#pragma unroll
            for (int i = 0; i < 16; i++) { s[i] = __shfl(idx, e + i); wr[i] = __shfl(w, e + i); }
#pragma unroll
            for (int i = 0; i < 16; i++)
                v[i] = ((const unsigned int*)(t + (size_t)s[i] * 128))[lane];
#pragma unroll
            for (int i = 0; i < 16; i++) {
                float lo = bf2f((unsigned short)(v[i] & 0xffffu));
                float hi = bf2f((unsigned short)(v[i] >> 16));
                if (i & 1) { sx1 += wr[i] * lo; sy1 += wr[i] * hi; }
                else       { sx0 += wr[i] * lo; sy0 += wr[i] * hi; }
            }
        }
    }
    axo = bias[2 * lane]     + dn * (sx0 + sx1);
    ayo = bias[2 * lane + 1] + dn * (sy0 + sy1);
}

// ---------------- aggregation kernel: one wave per node ----------------
__global__ __launch_bounds__(256) void agg_k(const unsigned short* t, unsigned short* outp,
                                             const float* bias, const int* rowptr,
                                             const unsigned short* colsrc, const float* wnorm,
                                             const float* dinv, int relu) {
    int gtid = blockIdx.x * 256 + threadIdx.x;
    int n = gtid >> 6;
    int lane = threadIdx.x & 63;
    if (n >= NN) return;
    float ax, ay;
    agg_node2(t, n, lane, bias, rowptr, colsrc, wnorm, dinv, ax, ay);
    if (relu) { ax = fmaxf(ax, 0.f); ay = fmaxf(ay, 0.f); }
    unsigned int o = (unsigned int)f2bf(ax) | ((unsigned int)f2bf(ay) << 16);
    ((unsigned int*)(outp + (size_t)n * 128))[lane] = o;
}

// ---------------- LDS-free bf16 GEMM (layer 2): A and W straight from global ----------------
__global__ __launch_bounds__(256) void gemm_direct_k(const unsigned short* in,
                                                     const unsigned short* wtp,
                                                     unsigned short* outp, int nrows) {
    int tid = threadIdx.x;
    int wv = tid >> 6, lane = tid & 63;
    int m = lane & 15, quad = lane >> 4;
    int row0 = blockIdx.x * 64;
    int arow = row0 + wv * 16 + m;
    int srow = (arow < nrows) ? arow : 0;
    const unsigned short* rp = in + (size_t)srow * 128;
    bf16x8 af[4];
#pragma unroll
    for (int ks = 0; ks < 4; ks++)
        af[ks] = *(const bf16x8*)&rp[ks * 32 + quad * 8];
    int grbase = row0 + wv * 16;
#pragma unroll
    for (int tile = 0; tile < 8; tile++) {
        f32x4 acc = {0.f, 0.f, 0.f, 0.f};
        int n = tile * 16 + m;
#pragma unroll
        for (int ks = 0; ks < 4; ks++) {
            bf16x8 bfr = *(const bf16x8*)&wtp[(size_t)n * 128 + ks * 32 + quad * 8];
            acc = __builtin_amdgcn_mfma_f32_16x16x32_bf16(af[ks], bfr, acc, 0, 0, 0);
        }
#pragma unroll
        for (int r = 0; r < 4; r++) {
            int orow = grbase + quad * 4 + r;
            if (orow < nrows) outp[(size_t)orow * 128 + n] = f2bf(acc[r]);
        }
    }
}

// ---------------- GEMM3': h2 @ C (128->16, split-bf16 C, double MFMA) -> [NN][16] ----------
__global__ __launch_bounds__(256) void gemm3_k(const unsigned short* in, const unsigned short* wlc,
                                               unsigned short* out16) {
    int tid = threadIdx.x;
    int wv = tid >> 6, lane = tid & 63;
    int m = lane & 15, quad = lane >> 4;
    int row0 = blockIdx.x * 64;
    int arow = row0 + wv * 16 + m;
    int srow = (arow < NN) ? arow : 0;
    const unsigned short* rp = in + (size_t)srow * 128;
    f32x4 acc = {0.f, 0.f, 0.f, 0.f};
#pragma unroll
    for (int ks = 0; ks < 4; ks++) {
        bf16x8 af = *(const bf16x8*)&rp[ks * 32 + quad * 8];
        bf16x8 bh = *(const bf16x8*)&wlc[m * 128 + ks * 32 + quad * 8];
        bf16x8 bl = *(const bf16x8*)&wlc[2048 + m * 128 + ks * 32 + quad * 8];
        acc = __builtin_amdgcn_mfma_f32_16x16x32_bf16(af, bh, acc, 0, 0, 0);
        acc = __builtin_amdgcn_mfma_f32_16x16x32_bf16(af, bl, acc, 0, 0, 0);
    }
    int grbase = row0 + wv * 16;
#pragma unroll
    for (int r = 0; r < 4; r++) {
        int orow = grbase + quad * 4 + r;
        if (orow < NN) out16[(size_t)orow * 16 + m] = f2bf(acc[r]);
    }
}

// ---------------- final agg on 16-wide rows + per-graph f32 pool ----------------
__global__ __launch_bounds__(256) void aggpool10_k(const unsigned short* t16, const int* rowptr,
                                                   const unsigned short* colsrc, const float* wnorm,
                                                   const float* dinv, const unsigned int* bu,
                                                   const int* flags, float* pooled) {
    __shared__ float sacc[4][16];
    __shared__ int sg[4];
    int tid = threadIdx.x, wv = tid >> 6, lane = tid & 63;
    int n = blockIdx.x * 4 + wv;
    int slot = lane >> 3, fi = lane & 7;
    int i64 = flags[1];
    int g = -1;
    float ax = 0.f, ay = 0.f, bx = 0.f, by = 0.f;
    if (n < NN) {
        g = (int)(i64 ? bu[2 * (size_t)n] : bu[n]);
        g = ((unsigned)g < NG) ? g : 0;
        float dn = dinv[n];
        int j0 = rowptr[n];
        int cnt = rowptr[n + 1] - j0;
        const unsigned int* tp = (const unsigned int*)t16;
        for (int e0 = 0; e0 < cnt; e0 += 64) {
            int mm = cnt - e0; if (mm > 64) mm = 64;
            int idx = 0; float w = 0.f;
            if (lane < mm) {
                idx = (int)colsrc[j0 + e0 + lane];
                idx = ((unsigned)idx < NN) ? idx : 0;
                w = wnorm[j0 + e0 + lane];
            }
            for (int e = 0; e < mm; e += 16) {
                int s0 = __shfl(idx, e + slot);      float w0 = __shfl(w, e + slot);
                int s1 = __shfl(idx, e + 8 + slot);  float w1 = __shfl(w, e + 8 + slot);
                unsigned int v0 = tp[(size_t)s0 * 8 + fi];
                unsigned int v1 = tp[(size_t)s1 * 8 + fi];
                ax += w0 * bf2f((unsigned short)(v0 & 0xffffu));
                ay += w0 * bf2f((unsigned short)(v0 >> 16));
                bx += w1 * bf2f((unsigned short)(v1 & 0xffffu));
                by += w1 * bf2f((unsigned short)(v1 >> 16));
            }
        }
        ax += bx; ay += by;
        ax += __shfl_xor(ax, 8);  ay += __shfl_xor(ay, 8);
        ax += __shfl_xor(ax, 16); ay += __shfl_xor(ay, 16);
        ax += __shfl_xor(ax, 32); ay += __shfl_xor(ay, 32);
        unsigned int sv = tp[(size_t)n * 8 + fi];
        float dn2 = dn * dn;
        ax = ax * dn + dn2 * bf2f((unsigned short)(sv & 0xffffu));
        ay = ay * dn + dn2 * bf2f((unsigned short)(sv >> 16));
    }
    if (slot == 0) { sacc[wv][2 * fi] = ax; sacc[wv][2 * fi + 1] = ay; }
    if (lane == 0) sg[wv] = g;
    __syncthreads();
    if (tid < 16) {
        float acc = 0.f; int curg = -1;
        for (int w2 = 0; w2 < 4; w2++) {
            int gg = sg[w2];
            if (gg < 0) continue;
            if (gg == curg) acc += sacc[w2][tid];
            else {
                if (curg >= 0) atomicAdd(&pooled[curg * 16 + tid], acc);
                curg = gg; acc = sacc[w2][tid];
            }
        }
        if (curg >= 0) atomicAdd(&pooled[curg * 16 + tid], acc);
    }
}

// ---------------- head: out[g][c] = pooled/cnt + b3@lin + lin_b ----------------
__global__ __launch_bounds__(64) void head10_k(const float* pooled, const int* starts,
                                               const float* blc, const float* lbf,
                                               void* outp, const int* flags) {
    int g = blockIdx.x, t = threadIdx.x;
    if (t >= NC) return;
    int c = starts[g + 1] - starts[g];
    float o;
    if (c > 0) o = pooled[g * 16 + t] / (float)c + blc[t] + lbf[t];
    else       o = lbf[t];   // empty graph: pooled=0 in reference -> out = lin_b
    if (flags[0]) ((unsigned short*)outp)[g * NC + t] = f2bf(o);
    else          ((float*)outp)[g * NC + t] = o;
}

extern "C" void kernel_launch(void* const* d_in, const int* in_sizes, int n_in,
                              void* d_out, int out_size, void* d_ws, size_t ws_size,
                              hipStream_t stream) {
    char* ws = (char*)d_ws;
    size_t off = 0;
    auto alloc = [&](size_t bytes) { size_t o = off; off = (off + bytes + 255) & ~(size_t)255; return o; };

    int*   flags  = (int*)(ws + alloc(32 * 4));
    int*   rowptr = (int*)(ws + alloc((size_t)(NN + 1) * 4));
    int*   starts = (int*)(ws + alloc((size_t)(NG + 1) * 4));
    int*   bkcnt  = (int*)(ws + alloc((size_t)256 * 4));
    int*   bkbase = (int*)(ws + alloc((size_t)512 * 4));
    int*   bkpos  = (int*)(ws + alloc((size_t)256 * 4));
    unsigned int* ebuck = (unsigned int*)(ws + alloc((size_t)EE * 4));
    unsigned short* colsrc = (unsigned short*)(ws + alloc((size_t)EE * 2));
    float* wnorm  = (float*)(ws + alloc((size_t)EE * 4));
    float* dinv   = (float*)(ws + alloc((size_t)NN * 4));
    unsigned short* wt  = (unsigned short*)(ws + alloc((size_t)3 * 16384 * 2));
    unsigned short* wlc = (unsigned short*)(ws + alloc((size_t)2 * 2048 * 2));
    float* blc    = (float*)(ws + alloc((size_t)16 * 4));
    float* bfv    = (float*)(ws + alloc((size_t)3 * 128 * 4));
    float* lwf    = (float*)(ws + alloc((size_t)1280 * 4));
    float* lbf    = (float*)(ws + alloc((size_t)16 * 4));
    float* pooled = (float*)(ws + alloc((size_t)NG * 128 * 4));
    unsigned short* tbuf = (unsigned short*)(ws + alloc((size_t)NN * 128 * 2));
    unsigned short* hbuf = (unsigned short*)(ws + alloc((size_t)NN * 128 * 2));

    const void* x = d_in[0];
    const unsigned int* eu = (const unsigned int*)d_in[1];
    const unsigned int* bu = (const unsigned int*)d_in[2];

    detect_k<<<1, 256, 0, stream>>>((const unsigned short*)x, eu, flags, bkcnt);

    // params-convert || graph bounds || bucket histogram
    combo2_k<<<CVB + NBK + NCHA, 256, 0, stream>>>(flags, d_in[3], d_in[4], d_in[5], d_in[6],
                                                   d_in[7], d_in[8], d_in[9], d_in[10],
                                                   wt, bfv, lwf, lbf, pooled,
                                                   eu, bkcnt, bu, starts);

    bkscan_k<<<1, 256, 0, stream>>>(bkcnt, bkbase, bkpos);

    // GEMM1 || CSR phase A || folded-weight build
    mega_k<<<GBK + NCHA + 9, 256, 0, stream>>>(flags, x, wt, tbuf, eu, bkpos, ebuck,
                                               wt + 32768, lwf, bfv + 256, wlc, blc);

    csrB_k<<<NBUCK, 256, 0, stream>>>(ebuck, bkbase, rowptr, dinv, colsrc);
    wnorm_k<<<(EE / 8 + 255) / 256, 256, 0, stream>>>(colsrc, dinv, wnorm);

    int agg_blocks = (NN * 64 + 255) / 256;   // one wave per node
    agg_k<<<agg_blocks, 256, 0, stream>>>(tbuf, hbuf, bfv, rowptr, colsrc, wnorm, dinv, 1);
    gemm_direct_k<<<GBK, 256, 0, stream>>>(hbuf, wt + 16384, tbuf, NN);
    agg_k<<<agg_blocks, 256, 0, stream>>>(tbuf, hbuf, bfv + 128, rowptr, colsrc, wnorm, dinv, 1);
    gemm3_k<<<GBK, 256, 0, stream>>>(hbuf, wlc, tbuf);   // h2 @ (W3 lin_w) -> [NN][16]
    aggpool10_k<<<(NN + 3) / 4, 256, 0, stream>>>(tbuf, rowptr, colsrc, wnorm, dinv,
                                                  bu, flags, pooled);

    head10_k<<<NG, 64, 0, stream>>>(pooled, starts, blc, lbf, d_out, flags);
}